// Round 8
// baseline (112.276 us; speedup 1.0000x reference)
//
#include <hip/hip_runtime.h>
#include <math.h>

// Problem constants (from reference setup_inputs)
#define NQ 2048
#define NB 8192
#define DIM 32

#define LOG2E 1.44269504088896340736f

typedef _Float16 half8 __attribute__((ext_vector_type(8)));
typedef float    f32x4 __attribute__((ext_vector_type(4)));

// ---------------- workspace layout (bytes, 64-B aligned) ----------------
#define WS_ACC 0         // 2*NQ f32
#define WS_B2  24640     // NB f32
#define WS_XBH 188480    // NB*DIM f16   (-2*(xb*w) rounded-then-scaled)

// Pre (xb only now — xq side fused into main): convert rows to f16 with
// norms computed FROM THE ROUNDED VALUES. XBh pre-scaled by -2 (exact).
__global__ __launch_bounds__(256) void relnw_pre(
    const float* __restrict__ xb, const float* __restrict__ w,
    _Float16* __restrict__ XBh, float* __restrict__ b2,
    float* __restrict__ acc)
{
    const int tid = threadIdx.x;
    const int gi  = blockIdx.x * 256 + tid;
    if (gi < 2 * NQ) acc[gi] = 0.f;      // zero atomic accumulators

    const int row = blockIdx.x * 64 + (tid >> 2);
    const int p   = tid & 3;             // 8-elem chunk within the row
    if (row >= NB) return;

    const float* src = xb + (size_t)row * DIM;
    _Float16*    dst = XBh + (size_t)row * DIM;

    const float4 xa  = ((const float4*)src)[p * 2];
    const float4 xbv = ((const float4*)src)[p * 2 + 1];
    const float4 wa  = ((const float4*)w)[p * 2];
    const float4 wb  = ((const float4*)w)[p * 2 + 1];
    const float xs[8]  = {xa.x, xa.y, xa.z, xa.w, xbv.x, xbv.y, xbv.z, xbv.w};
    const float ws_[8] = {wa.x, wa.y, wa.z, wa.w, wb.x, wb.y, wb.z, wb.w};

    half8 h;
    float s = 0.f;
#pragma unroll
    for (int c = 0; c < 8; ++c) {
        float t = xs[c] * ws_[c];
        _Float16 hh = (_Float16)t;       // the rounding
        float th = (float)hh;
        s = fmaf(th, th, s);             // norm of the ROUNDED vector
        h[c] = (_Float16)(th * -2.f);    // exact scaling
    }
    *(half8*)(dst + p * 8) = h;          // coalesced 16-B store

    // row-norm: reduce over the 4 chunk-lanes (low 2 lane bits)
    s += __shfl_xor(s, 1, 64);
    s += __shfl_xor(s, 2, 64);
    if (p == 0) b2[row] = s;
}

// Main: grid (8, 128) = 1024 blocks, 256 threads (4 waves), 2 blocks/CU.
// Block task: 16 queries x 1024 bg cols = 64 MFMA tiles (16 per wave).
//
// R14 (mono-stage): R4(512B,2 drains) ~ R5(256B,counted) ~ R6(1KB coop) ~
// R7(no swz) all ~19.4us main — staging shape/schedule exhausted. The
// 6.5-TB/s fills run with ZERO barriers and deep per-thread ILP at 8.5%
// occupancy. This version mimics that: stage the block's ENTIRE 64-KB r
// slab in one shot (16 gl_lds/wave = 16 KB/wave in flight, 144 KB/CU),
// ONE vmcnt(0), ONE barrier, then compute all 16 tiles/wave with zero
// further sync. LDS 72 KB -> 2 blocks/CU (fills prove occupancy is not
// needed for BW; VALU work ~2.7us/SIMD hides under the stream).
//
// R14 (fusion): xq/q2/qfrag computed INLINE per block (4 loads + ~30 VALU
// + 2 shfls) — bit-identical to pre's path: same products, same f16
// rounding, same pairwise tree (p0+p1)+(p2+p3) with quad as the chunk
// index. pre shrinks to xb-only (128 blocks). absmax unchanged.
//
// LDS r reads are 16-way bank-aliased (m*4096 stride) — R6/R7 equivalence
// showed LDS conflicts are invisible under the HBM stream; keep linear.
//
// R8 lesson (keep): __launch_bounds__(256,2) — (256,4) caps VGPR at 64 and
// spills everything. R5 lesson (keep): no __threadfence / fused finalize.
#define GLDS(GSRC, LDST)                                                    \
  __builtin_amdgcn_global_load_lds(                                         \
      (const __attribute__((address_space(1))) void*)(GSRC),                \
      (__attribute__((address_space(3))) void*)(LDST), 16, 0, 0)

#define SBAR __builtin_amdgcn_sched_barrier(0)

__global__ __launch_bounds__(256, 2) void relnw_main(
    const _Float16* __restrict__ XBh,  // (NB, DIM), pre-scaled by -2
    const float* __restrict__ b2,      // (NB,)
    const float* __restrict__ yb,      // (NB,)
    const float* __restrict__ xq,      // (NQ, DIM)
    const float* __restrict__ w,       // (DIM,)
    const float* __restrict__ r,       // (NQ, NB)
    const float* __restrict__ sigma,   // (1,)
    const float* __restrict__ rscale,  // (1,)
    float* __restrict__ acc)           // [0:NQ]=sum_k, [NQ:2NQ]=sum_k*y
{
    // LDS: 16 r rows x 4 KB + 4-KB b2 + 4-KB yb = 73728 B -> 2 blocks/CU
    __shared__ char lds[16 * 4096 + 4096 + 4096];

    const int tid  = threadIdx.x;
    const int lane = tid & 63;
    const int wid  = tid >> 6;
    const int m    = lane & 15;   // query col (D) / A-row feeder
    const int quad = lane >> 4;   // 0..3

    const int q0    = blockIdx.y * 16;
    const int bcol0 = blockIdx.x * 1024;   // block's 1024 bg cols

    float* b2l = (float*)(lds + 65536);
    float* ybl = (float*)(lds + 69632);

    const float c1 = -LOG2E / sigma[0];   // coeff on dist (log2 space)
    const float c2 =  LOG2E * rscale[0];  // coeff on r

    // ---- issue xq/w register loads (oldest), then the full 64-KB r slab
    //      + 8-KB aux via gl_lds: 18 VMEM per wave in flight, one drain ----
    const float4 qa = ((const float4*)(xq + (size_t)(q0 + m) * DIM))[quad * 2];
    const float4 qb = ((const float4*)(xq + (size_t)(q0 + m) * DIM))[quad * 2 + 1];
    const float4 wa = ((const float4*)w)[quad * 2];
    const float4 wb = ((const float4*)w)[quad * 2 + 1];

#pragma unroll
    for (int j = 0; j < 4; ++j) {
        const int rw = wid * 4 + j;       // r row (query-local) this wave stages
        const char* rbase = (const char*)(r + (size_t)(q0 + rw) * NB + bcol0)
                            + lane * 16;
#pragma unroll
        for (int ck = 0; ck < 4; ++ck)    // 4 x 1-KB contiguous bursts per row
            GLDS(rbase + ck * 1024, lds + rw * 4096 + ck * 1024);
    }
    GLDS((const char*)(b2 + bcol0) + wid * 1024 + lane * 16,
         (char*)b2l + wid * 1024);
    GLDS((const char*)(yb + bcol0) + wid * 1024 + lane * 16,
         (char*)ybl + wid * 1024);

    // ---- qfrag/q2 inline (identical math to old pre, chunk index = quad) ----
    const float xs[8]  = {qa.x, qa.y, qa.z, qa.w, qb.x, qb.y, qb.z, qb.w};
    const float ws_[8] = {wa.x, wa.y, wa.z, wa.w, wb.x, wb.y, wb.z, wb.w};
    half8 qfrag;
    float s = 0.f;
#pragma unroll
    for (int c = 0; c < 8; ++c) {
        float t = xs[c] * ws_[c];
        _Float16 hh = (_Float16)t;
        float th = (float)hh;
        s = fmaf(th, th, s);
        qfrag[c] = hh;                    // scale=1: (f16)th == hh bit-exact
    }
    s += __shfl_xor(s, 16, 64);           // pairwise tree over quads —
    s += __shfl_xor(s, 32, 64);           // same shape as pre's (1,2) tree
    const float q2s = s;

    SBAR;
    asm volatile("s_waitcnt vmcnt(0)" ::: "memory");  // whole slab resident
    SBAR;
    __builtin_amdgcn_s_barrier();                     // block-wide

    // ---- compute all 16 tiles, zero further sync ----
    float sk = 0.f, sky = 0.f;
#pragma unroll
    for (int it = 0; it < 16; ++it) {
        const int col0 = bcol0 + wid * 256 + it * 16;   // tile's bg col base
        const half8 af = *(const half8*)(XBh +
                         (size_t)(col0 + m) * DIM + quad * 8);  // L2-warm
        const int co = wid * 256 + it * 16 + quad * 4;
        const f32x4 bb = *(const f32x4*)(b2l + co);     // quad-broadcast
        const f32x4 yv = *(const f32x4*)(ybl + co);     // quad-broadcast
        const f32x4 rr = *(const f32x4*)(lds + m * 4096 +
                             wid * 1024 + it * 64 + quad * 16);

        f32x4 cin;
#pragma unroll
        for (int g = 0; g < 4; ++g) cin[g] = q2s + bb[g];

        // D = q2 + b2 - 2*dot = d2 ; rows = bg, cols = query
        const f32x4 d2v = __builtin_amdgcn_mfma_f32_16x16x32_f16(
            af, qfrag, cin, 0, 0, 0);

#pragma unroll
        for (int g = 0; g < 4; ++g) {
            float d2   = fmaxf(d2v[g], 0.f);
            float dist = __builtin_amdgcn_sqrtf(d2);
            float e    = fmaf(dist, c1, rr[g] * c2);    // log2 space
            float k    = __builtin_amdgcn_exp2f(e);
            sk += k;
            sky = fmaf(k, yv[g], sky);
        }
    }

    // All 4 values of a lane belong to query q0+m; reduce across quads.
    sk  += __shfl_xor(sk, 16, 64);
    sk  += __shfl_xor(sk, 32, 64);
    sky += __shfl_xor(sky, 16, 64);
    sky += __shfl_xor(sky, 32, 64);
    if (lane < 16) {
        atomicAdd(acc + (q0 + m),      sk);
        atomicAdd(acc + NQ + (q0 + m), sky);
    }
}

__global__ __launch_bounds__(256) void relnw_finalize(
    const float* __restrict__ acc, float* __restrict__ out)
{
    int q = blockIdx.x * 256 + threadIdx.x;
    if (q < NQ)
        out[q] = acc[NQ + q] / (acc[q] + 1e-8f);
}

extern "C" void kernel_launch(void* const* d_in, const int* in_sizes, int n_in,
                              void* d_out, int out_size, void* d_ws, size_t ws_size,
                              hipStream_t stream) {
    const float* xb     = (const float*)d_in[0]; // (8192,32)
    const float* yb     = (const float*)d_in[1]; // (8192,)
    const float* xq     = (const float*)d_in[2]; // (2048,32)
    const float* r      = (const float*)d_in[3]; // (2048,8192)
    const float* sigma  = (const float*)d_in[4]; // (1,)
    const float* rscale = (const float*)d_in[5]; // (1,)
    const float* w      = (const float*)d_in[6]; // (32,)
    float* out = (float*)d_out;

    char* ws = (char*)d_ws;
    float*    acc = (float*)(ws + WS_ACC);
    float*    b2  = (float*)(ws + WS_B2);
    _Float16* XBh = (_Float16*)(ws + WS_XBH);

    relnw_pre<<<NB / 64, 256, 0, stream>>>(xb, w, XBh, b2, acc);

    dim3 grid(NB / 1024, NQ / 16);  // (8, 128) = 1024 blocks
    relnw_main<<<grid, 256, 0, stream>>>(XBh, b2, yb, xq, w, r,
                                         sigma, rscale, acc);

    relnw_finalize<<<(NQ + 255) / 256, 256, 0, stream>>>(acc, out);
}